// Round 8
// baseline (172.651 us; speedup 1.0000x reference)
//
#include <hip/hip_runtime.h>
#include <math.h>

#define BB 4
#define RR 64
#define SS 512
#define HH 768
#define EE 64
#define SEGD 128
#define NT 6
#define NC 13
#define NP 3
#define NO (NT + NC + NP)        // 22
#define REP 2560                 // 2*H + 2*SEG + H
#define NEGV -1e30f

#define RPG 8                    // relations per block
#define NGRP (RR / RPG)          // 8
#define SC 16                    // S chunks (R2's proven best)
#define ROWS (SS / SC)           // 32
#define NBLK (BB * NGRP * SC)    // 512 blocks
#define PART_ELEMS ((size_t)BB * RR * SC * HH)   // 3,145,728 floats

// ---- single kernel: masked-max partials + last-arriving block finalizes ----
__global__ __launch_bounds__(256, 2)
void rel_fused_atomic(const float* __restrict__ hidden,     // [B,S,H]
                      const int*   __restrict__ rel_pairs,  // [B,R,2]
                      const int*   __restrict__ rel_masks,  // [B,R,S]
                      const float* __restrict__ span,       // [B,E,H]
                      const float* __restrict__ segs,       // [B,E,SEG]
                      const float* __restrict__ Wt, const float* __restrict__ bt,
                      const float* __restrict__ Wc, const float* __restrict__ bc,
                      const float* __restrict__ Wp, const float* __restrict__ bp,
                      float* __restrict__ ws,               // [B*R, SC, H]
                      unsigned int* __restrict__ cnt,       // [B*R], zeroed per call
                      float* __restrict__ out)
{
    const int bid = blockIdx.x;
    const int t   = threadIdx.x;
    const int sc  = bid % SC;
    const int grp = (bid / SC) % NGRP;
    const int b   = bid / (SC * NGRP);
    const int s0  = sc * ROWS;
    const int r0  = grp * RPG;

    __shared__ float        sadd[RPG * ROWS];   // 1 KB
    __shared__ float        feat[REP];          // 10 KB
    __shared__ float        red[4][NO];
    __shared__ unsigned int wins[RPG];

    // ================= phase A: branchless masked max (R2-exact) =============
    {
        const int r  = t / ROWS;
        const int s  = t - r * ROWS;
        const int mv = rel_masks[((size_t)(b * RR + r0 + r)) * SS + s0 + s];
        sadd[t] = mv ? 0.f : NEGV;
    }
    __syncthreads();

    float m[RPG][3];
#pragma unroll
    for (int r = 0; r < RPG; ++r) {
        m[r][0] = -INFINITY; m[r][1] = -INFINITY; m[r][2] = -INFINITY;
    }

#pragma unroll 2
    for (int s = 0; s < ROWS; ++s) {
        const float* hp = hidden + ((size_t)(b * SS + s0 + s)) * HH;
        const float v0 = hp[t];
        const float v1 = hp[t + 256];
        const float v2 = hp[t + 512];
#pragma unroll
        for (int r = 0; r < RPG; ++r) {
            const float a = sadd[r * ROWS + s];
            m[r][0] = fmaxf(m[r][0], v0 + a);
            m[r][1] = fmaxf(m[r][1], v1 + a);
            m[r][2] = fmaxf(m[r][2], v2 + a);
        }
    }

#pragma unroll
    for (int r = 0; r < RPG; ++r) {
        float* wp = ws + (((size_t)(b * RR + r0 + r)) * SC + sc) * HH;
        wp[t]       = m[r][0];
        wp[t + 256] = m[r][1];
        wp[t + 512] = m[r][2];
    }

    // release: make partials device-visible, then signal
    __threadfence();
    __syncthreads();
    if (t < RPG) wins[t] = atomicAdd(&cnt[b * RR + r0 + t], 1u);
    __syncthreads();
    __threadfence();   // acquire side for any relation we won

    // ================= phase B: finalize relations we completed last =========
    for (int k = 0; k < RPG; ++k) {
        if (wins[k] != SC - 1) continue;     // uniform (shared) -> no divergence
        const int br = b * RR + r0 + k;

        const int i0 = rel_pairs[(size_t)br * 2 + 0];
        const int i1 = rel_pairs[(size_t)br * 2 + 1];

        // gather pair span / seg embeddings (R2 layout)
        const float* sp0 = span + ((size_t)b * EE + i0) * HH;
        const float* sp1 = span + ((size_t)b * EE + i1) * HH;
        feat[t]            = sp0[t];
        feat[t + 256]      = sp0[t + 256];
        feat[t + 512]      = sp0[t + 512];
        feat[HH + t]       = sp1[t];
        feat[HH + t + 256] = sp1[t + 256];
        feat[HH + t + 512] = sp1[t + 512];
        const float* sg0 = segs + ((size_t)b * EE + i0) * SEGD;
        const float* sg1 = segs + ((size_t)b * EE + i1) * SEGD;
        if (t < SEGD) feat[2 * HH + t] = sg0[t];
        else          feat[2 * HH + SEGD + (t - SEGD)] = sg1[t - SEGD];

        // reduce SC partial maxes
        float m0 = -INFINITY, m1 = -INFINITY, m2 = -INFINITY;
#pragma unroll 4
        for (int c = 0; c < SC; ++c) {
            const float* wp = ws + ((size_t)br * SC + c) * HH;
            m0 = fmaxf(m0, wp[t]);
            m1 = fmaxf(m1, wp[t + 256]);
            m2 = fmaxf(m2, wp[t + 512]);
        }
        if (m0 < -1e29f) m0 = 0.f;
        if (m1 < -1e29f) m1 = 0.f;
        if (m2 < -1e29f) m2 = 0.f;
        const int CTX0 = 2 * HH + 2 * SEGD;   // 1792
        feat[CTX0 + t]       = m0;
        feat[CTX0 + t + 256] = m1;
        feat[CTX0 + t + 512] = m2;
        __syncthreads();

        // 2560 x 22 matvec (R2-exact)
        float acc[NO];
#pragma unroll
        for (int o = 0; o < NO; ++o) acc[o] = 0.f;
        for (int f = t; f < REP; f += 256) {
            const float fv = feat[f];
            const float* wt = Wt + (size_t)f * NT;
            const float* wc = Wc + (size_t)f * NC;
            const float* wp = Wp + (size_t)f * NP;
#pragma unroll
            for (int o = 0; o < NT; ++o) acc[o]           += fv * wt[o];
#pragma unroll
            for (int o = 0; o < NC; ++o) acc[NT + o]      += fv * wc[o];
#pragma unroll
            for (int o = 0; o < NP; ++o) acc[NT + NC + o] += fv * wp[o];
        }
#pragma unroll
        for (int o = 0; o < NO; ++o) {
#pragma unroll
            for (int off = 32; off > 0; off >>= 1)
                acc[o] += __shfl_down(acc[o], off, 64);
        }
        const int wid  = t >> 6;
        const int lane = t & 63;
        if (lane == 0) {
#pragma unroll
            for (int o = 0; o < NO; ++o) red[wid][o] = acc[o];
        }
        __syncthreads();

        if (t < NO) {
            const float v = red[0][t] + red[1][t] + red[2][t] + red[3][t];
            if (t < NT) {
                out[(size_t)br * NT + t] = v + bt[t];
            } else if (t < NT + NC) {
                const int o = t - NT;
                out[(size_t)BB * RR * NT + (size_t)br * NC + o] = v + bc[o];
            } else {
                const int o = t - NT - NC;
                out[(size_t)BB * RR * (NT + NC) + (size_t)br * NP + o] = v + bp[o];
            }
        }
        __syncthreads();   // protect feat/red before a possible next finalize
    }
}

// ---------------- fallback: fused single kernel (if ws too small) ----------------
__global__ __launch_bounds__(256)
void rel_cls_fused(const float* __restrict__ hidden,
                   const int*   __restrict__ rel_pairs,
                   const int*   __restrict__ rel_masks,
                   const float* __restrict__ span,
                   const float* __restrict__ segs,
                   const float* __restrict__ Wt, const float* __restrict__ bt,
                   const float* __restrict__ Wc, const float* __restrict__ bc,
                   const float* __restrict__ Wp, const float* __restrict__ bp,
                   float* __restrict__ out)
{
    const int br = blockIdx.x;
    const int b  = br / RR;
    const int t  = threadIdx.x;

    __shared__ float sadd[SS];
    __shared__ float feat[REP];
    __shared__ float red[4][NO];

    const int* mrow = rel_masks + (size_t)br * SS;
    sadd[t]       = mrow[t] ? 0.f : NEGV;
    sadd[t + 256] = mrow[t + 256] ? 0.f : NEGV;

    const int i0 = rel_pairs[(size_t)br * 2 + 0];
    const int i1 = rel_pairs[(size_t)br * 2 + 1];
    const float* sp0 = span + ((size_t)b * EE + i0) * HH;
    const float* sp1 = span + ((size_t)b * EE + i1) * HH;
    feat[t]            = sp0[t];
    feat[t + 256]      = sp0[t + 256];
    feat[t + 512]      = sp0[t + 512];
    feat[HH + t]       = sp1[t];
    feat[HH + t + 256] = sp1[t + 256];
    feat[HH + t + 512] = sp1[t + 512];
    const float* sg0 = segs + ((size_t)b * EE + i0) * SEGD;
    const float* sg1 = segs + ((size_t)b * EE + i1) * SEGD;
    if (t < SEGD) feat[2 * HH + t] = sg0[t];
    else          feat[2 * HH + SEGD + (t - SEGD)] = sg1[t - SEGD];
    __syncthreads();

    float m0 = -INFINITY, m1 = -INFINITY, m2 = -INFINITY;
#pragma unroll 8
    for (int s = 0; s < SS; ++s) {
        const float* hp = hidden + ((size_t)b * SS + s) * HH;
        const float a = sadd[s];
        m0 = fmaxf(m0, hp[t] + a);
        m1 = fmaxf(m1, hp[t + 256] + a);
        m2 = fmaxf(m2, hp[t + 512] + a);
    }
    if (m0 < -1e29f) m0 = 0.f;
    if (m1 < -1e29f) m1 = 0.f;
    if (m2 < -1e29f) m2 = 0.f;
    const int CTX0 = 2 * HH + 2 * SEGD;
    feat[CTX0 + t]       = m0;
    feat[CTX0 + t + 256] = m1;
    feat[CTX0 + t + 512] = m2;
    __syncthreads();

    float acc[NO];
#pragma unroll
    for (int o = 0; o < NO; ++o) acc[o] = 0.f;
    for (int f = t; f < REP; f += 256) {
        const float fv = feat[f];
        const float* wt = Wt + (size_t)f * NT;
        const float* wc = Wc + (size_t)f * NC;
        const float* wp = Wp + (size_t)f * NP;
#pragma unroll
        for (int o = 0; o < NT; ++o) acc[o]           += fv * wt[o];
#pragma unroll
        for (int o = 0; o < NC; ++o) acc[NT + o]      += fv * wc[o];
#pragma unroll
        for (int o = 0; o < NP; ++o) acc[NT + NC + o] += fv * wp[o];
    }
#pragma unroll
    for (int o = 0; o < NO; ++o) {
#pragma unroll
        for (int off = 32; off > 0; off >>= 1)
            acc[o] += __shfl_down(acc[o], off, 64);
    }
    const int wid  = t >> 6;
    const int lane = t & 63;
    if (lane == 0) {
#pragma unroll
        for (int o = 0; o < NO; ++o) red[wid][o] = acc[o];
    }
    __syncthreads();

    if (t < NO) {
        const float v = red[0][t] + red[1][t] + red[2][t] + red[3][t];
        if (t < NT) {
            out[(size_t)br * NT + t] = v + bt[t];
        } else if (t < NT + NC) {
            const int o = t - NT;
            out[(size_t)BB * RR * NT + (size_t)br * NC + o] = v + bc[o];
        } else {
            const int o = t - NT - NC;
            out[(size_t)BB * RR * (NT + NC) + (size_t)br * NP + o] = v + bp[o];
        }
    }
}

extern "C" void kernel_launch(void* const* d_in, const int* in_sizes, int n_in,
                              void* d_out, int out_size, void* d_ws, size_t ws_size,
                              hipStream_t stream) {
    const float* hidden = (const float*)d_in[0];
    const int*   pairs  = (const int*)d_in[1];
    const int*   masks  = (const int*)d_in[2];
    const float* span   = (const float*)d_in[4];
    const float* segs   = (const float*)d_in[5];
    const float* Wt     = (const float*)d_in[6];
    const float* bt     = (const float*)d_in[7];
    const float* Wc     = (const float*)d_in[8];
    const float* bc     = (const float*)d_in[9];
    const float* Wp     = (const float*)d_in[10];
    const float* bp     = (const float*)d_in[11];
    float* out = (float*)d_out;
    float* ws  = (float*)d_ws;

    const size_t need = PART_ELEMS * sizeof(float) + (size_t)BB * RR * sizeof(unsigned int);

    if (ws_size >= need) {
        unsigned int* cnt = (unsigned int*)(ws + PART_ELEMS);
        // zero the per-relation arrival counters (tiny, graph-capture-safe)
        hipMemsetAsync((void*)cnt, 0, (size_t)BB * RR * sizeof(unsigned int), stream);
        hipLaunchKernelGGL(rel_fused_atomic, dim3(NBLK), dim3(256), 0, stream,
                           hidden, pairs, masks, span, segs,
                           Wt, bt, Wc, bc, Wp, bp, ws, cnt, out);
    } else {
        hipLaunchKernelGGL(rel_cls_fused, dim3(BB * RR), dim3(256), 0, stream,
                           hidden, pairs, masks, span, segs,
                           Wt, bt, Wc, bc, Wp, bp, out);
    }
}

// Round 9
// 27.256 us; speedup vs baseline: 6.3345x; 6.3345x over previous
//
#include <hip/hip_runtime.h>
#include <math.h>

#define BB 4
#define RR 64
#define SS 512
#define HH 768
#define EE 64
#define SEGD 128
#define NT 6
#define NC 13
#define NP 3
#define NO (NT + NC + NP)        // 22
#define REP 2560                 // 2*H + 2*SEG + H
#define NEGV -1e30f

#define HC 8                     // h-columns per p1 block
#define NHB (HH / HC)            // 96
#define SCP 4                    // s-chunks
#define SROWS (SS / SCP)         // 128
#define NB1 (BB * NHB * SCP)     // 1536 blocks
#define PART_ELEMS ((size_t)BB * RR * SCP * HH)   // 786432 floats (3 MB)

// ---------------- p1: lane=relation masked max; hidden read once chip-wide ----
__global__ __launch_bounds__(256, 6)
void p1_ctx(const float* __restrict__ hidden,      // [B,S,H]
            const int*   __restrict__ rel_masks,   // [B,R,S]
            float* __restrict__ ws)                // [B*R][SCP][HH]
{
    const int bid = blockIdx.x;
    const int sc  = bid & 3;                // SCP = 4
    const int hc  = (bid >> 2) % NHB;
    const int b   = bid / (4 * NHB);
    const int t   = threadIdx.x;
    const int w   = t >> 6;                 // wave id: s-subwindow
    const int r   = t & 63;                 // lane = relation
    const int h0  = hc * HC;
    const int s0  = sc * SROWS;

    __shared__ unsigned char keep[64 * 132];   // [r][s], +4 pad -> conflict-free reads
    __shared__ float part[4 * 64 * 9];         // [w][r][j(+1 pad)]

    // ---- stage mask bytes, coalesced (consecutive t -> consecutive s) ----
    const int mbase = b * RR * SS + s0;
    for (int k = t; k < 64 * SROWS; k += 256) {
        const int rr = k >> 7;              // k / 128
        const int s  = k & 127;
        keep[rr * 132 + s] = (unsigned char)(rel_masks[(size_t)mbase + rr * SS + s] != 0);
    }
    __syncthreads();

    // ---- main loop: wave w covers 32 s; per s one uniform 32B hidden load ----
    float a0 = -INFINITY, a1 = -INFINITY, a2 = -INFINITY, a3 = -INFINITY;
    float a4 = -INFINITY, a5 = -INFINITY, a6 = -INFINITY, a7 = -INFINITY;
    const float* hp = hidden + ((size_t)b * SS + s0 + w * 32) * HH + h0;
    const unsigned char* kp = &keep[r * 132 + w * 32];
#pragma unroll 4
    for (int s = 0; s < 32; ++s) {
        const float4 va = *reinterpret_cast<const float4*>(hp + (size_t)s * HH);
        const float4 vb = *reinterpret_cast<const float4*>(hp + (size_t)s * HH + 4);
        const float a = kp[s] ? 0.f : NEGV;
        a0 = fmaxf(a0, va.x + a);
        a1 = fmaxf(a1, va.y + a);
        a2 = fmaxf(a2, va.z + a);
        a3 = fmaxf(a3, va.w + a);
        a4 = fmaxf(a4, vb.x + a);
        a5 = fmaxf(a5, vb.y + a);
        a6 = fmaxf(a6, vb.z + a);
        a7 = fmaxf(a7, vb.w + a);
    }

    // ---- cross-wave LDS reduce (pad 9 -> conflict-free) ----
    float* pp = &part[(w * 64 + r) * 9];
    pp[0] = a0; pp[1] = a1; pp[2] = a2; pp[3] = a3;
    pp[4] = a4; pp[5] = a5; pp[6] = a6; pp[7] = a7;
    __syncthreads();

    if (w == 0) {
        float* wp = ws + (((size_t)(b * RR + r)) * SCP + sc) * HH + h0;
#pragma unroll
        for (int j = 0; j < 8; ++j) {
            float v = part[(0 * 64 + r) * 9 + j];
            v = fmaxf(v, part[(1 * 64 + r) * 9 + j]);
            v = fmaxf(v, part[(2 * 64 + r) * 9 + j]);
            v = fmaxf(v, part[(3 * 64 + r) * 9 + j]);
            wp[j] = v;
        }
    }
}

// ---------------- p2: reduce 4 partials, gather, matvec (R2-exact shape) ------
__global__ __launch_bounds__(256)
void p2_head(const float* __restrict__ ws,          // [B*R][SCP][HH]
             const int*   __restrict__ rel_pairs,   // [B,R,2]
             const float* __restrict__ span,        // [B,E,H]
             const float* __restrict__ segs,        // [B,E,SEG]
             const float* __restrict__ Wt, const float* __restrict__ bt,
             const float* __restrict__ Wc, const float* __restrict__ bc,
             const float* __restrict__ Wp, const float* __restrict__ bp,
             float* __restrict__ out)
{
    const int br = blockIdx.x;
    const int b  = br / RR;
    const int t  = threadIdx.x;

    __shared__ float feat[REP];
    __shared__ float red[4][NO];

    const int i0 = rel_pairs[(size_t)br * 2 + 0];
    const int i1 = rel_pairs[(size_t)br * 2 + 1];

    // gather pair span / seg embeddings
    const float* sp0 = span + ((size_t)b * EE + i0) * HH;
    const float* sp1 = span + ((size_t)b * EE + i1) * HH;
    feat[t]            = sp0[t];
    feat[t + 256]      = sp0[t + 256];
    feat[t + 512]      = sp0[t + 512];
    feat[HH + t]       = sp1[t];
    feat[HH + t + 256] = sp1[t + 256];
    feat[HH + t + 512] = sp1[t + 512];
    const float* sg0 = segs + ((size_t)b * EE + i0) * SEGD;
    const float* sg1 = segs + ((size_t)b * EE + i1) * SEGD;
    if (t < SEGD) feat[2 * HH + t] = sg0[t];
    else          feat[2 * HH + SEGD + (t - SEGD)] = sg1[t - SEGD];

    // reduce SCP=4 partial maxes (coalesced)
    const float* wbase = ws + (size_t)br * SCP * HH;
    float m0 = -INFINITY, m1 = -INFINITY, m2 = -INFINITY;
#pragma unroll
    for (int c = 0; c < SCP; ++c) {
        const float* wp = wbase + (size_t)c * HH;
        m0 = fmaxf(m0, wp[t]);
        m1 = fmaxf(m1, wp[t + 256]);
        m2 = fmaxf(m2, wp[t + 512]);
    }
    // all-masked rows collapse to ~-1e30; reference zeroes them
    if (m0 < -1e29f) m0 = 0.f;
    if (m1 < -1e29f) m1 = 0.f;
    if (m2 < -1e29f) m2 = 0.f;
    const int CTX0 = 2 * HH + 2 * SEGD;   // 1792
    feat[CTX0 + t]       = m0;
    feat[CTX0 + t + 256] = m1;
    feat[CTX0 + t + 512] = m2;
    __syncthreads();

    // 2560 x 22 matvec
    float acc[NO];
#pragma unroll
    for (int o = 0; o < NO; ++o) acc[o] = 0.f;
    for (int f = t; f < REP; f += 256) {
        const float fv = feat[f];
        const float* wt = Wt + (size_t)f * NT;
        const float* wc = Wc + (size_t)f * NC;
        const float* wp = Wp + (size_t)f * NP;
#pragma unroll
        for (int o = 0; o < NT; ++o) acc[o]           += fv * wt[o];
#pragma unroll
        for (int o = 0; o < NC; ++o) acc[NT + o]      += fv * wc[o];
#pragma unroll
        for (int o = 0; o < NP; ++o) acc[NT + NC + o] += fv * wp[o];
    }
#pragma unroll
    for (int o = 0; o < NO; ++o) {
#pragma unroll
        for (int off = 32; off > 0; off >>= 1)
            acc[o] += __shfl_down(acc[o], off, 64);
    }
    const int wid  = t >> 6;
    const int lane = t & 63;
    if (lane == 0) {
#pragma unroll
        for (int o = 0; o < NO; ++o) red[wid][o] = acc[o];
    }
    __syncthreads();

    if (t < NO) {
        const float v = red[0][t] + red[1][t] + red[2][t] + red[3][t];
        if (t < NT) {
            out[(size_t)br * NT + t] = v + bt[t];
        } else if (t < NT + NC) {
            const int o = t - NT;
            out[(size_t)BB * RR * NT + (size_t)br * NC + o] = v + bc[o];
        } else {
            const int o = t - NT - NC;
            out[(size_t)BB * RR * (NT + NC) + (size_t)br * NP + o] = v + bp[o];
        }
    }
}

// ---------------- fallback: fused single kernel (if ws too small) ----------------
__global__ __launch_bounds__(256)
void rel_cls_fused(const float* __restrict__ hidden,
                   const int*   __restrict__ rel_pairs,
                   const int*   __restrict__ rel_masks,
                   const float* __restrict__ span,
                   const float* __restrict__ segs,
                   const float* __restrict__ Wt, const float* __restrict__ bt,
                   const float* __restrict__ Wc, const float* __restrict__ bc,
                   const float* __restrict__ Wp, const float* __restrict__ bp,
                   float* __restrict__ out)
{
    const int br = blockIdx.x;
    const int b  = br / RR;
    const int t  = threadIdx.x;

    __shared__ float sadd[SS];
    __shared__ float feat[REP];
    __shared__ float red[4][NO];

    const int* mrow = rel_masks + (size_t)br * SS;
    sadd[t]       = mrow[t] ? 0.f : NEGV;
    sadd[t + 256] = mrow[t + 256] ? 0.f : NEGV;

    const int i0 = rel_pairs[(size_t)br * 2 + 0];
    const int i1 = rel_pairs[(size_t)br * 2 + 1];
    const float* sp0 = span + ((size_t)b * EE + i0) * HH;
    const float* sp1 = span + ((size_t)b * EE + i1) * HH;
    feat[t]            = sp0[t];
    feat[t + 256]      = sp0[t + 256];
    feat[t + 512]      = sp0[t + 512];
    feat[HH + t]       = sp1[t];
    feat[HH + t + 256] = sp1[t + 256];
    feat[HH + t + 512] = sp1[t + 512];
    const float* sg0 = segs + ((size_t)b * EE + i0) * SEGD;
    const float* sg1 = segs + ((size_t)b * EE + i1) * SEGD;
    if (t < SEGD) feat[2 * HH + t] = sg0[t];
    else          feat[2 * HH + SEGD + (t - SEGD)] = sg1[t - SEGD];
    __syncthreads();

    float m0 = -INFINITY, m1 = -INFINITY, m2 = -INFINITY;
#pragma unroll 8
    for (int s = 0; s < SS; ++s) {
        const float* hp = hidden + ((size_t)b * SS + s) * HH;
        const float a = sadd[s];
        m0 = fmaxf(m0, hp[t] + a);
        m1 = fmaxf(m1, hp[t + 256] + a);
        m2 = fmaxf(m2, hp[t + 512] + a);
    }
    if (m0 < -1e29f) m0 = 0.f;
    if (m1 < -1e29f) m1 = 0.f;
    if (m2 < -1e29f) m2 = 0.f;
    const int CTX0 = 2 * HH + 2 * SEGD;
    feat[CTX0 + t]       = m0;
    feat[CTX0 + t + 256] = m1;
    feat[CTX0 + t + 512] = m2;
    __syncthreads();

    float acc[NO];
#pragma unroll
    for (int o = 0; o < NO; ++o) acc[o] = 0.f;
    for (int f = t; f < REP; f += 256) {
        const float fv = feat[f];
        const float* wt = Wt + (size_t)f * NT;
        const float* wc = Wc + (size_t)f * NC;
        const float* wp = Wp + (size_t)f * NP;
#pragma unroll
        for (int o = 0; o < NT; ++o) acc[o]           += fv * wt[o];
#pragma unroll
        for (int o = 0; o < NC; ++o) acc[NT + o]      += fv * wc[o];
#pragma unroll
        for (int o = 0; o < NP; ++o) acc[NT + NC + o] += fv * wp[o];
    }
#pragma unroll
    for (int o = 0; o < NO; ++o) {
#pragma unroll
        for (int off = 32; off > 0; off >>= 1)
            acc[o] += __shfl_down(acc[o], off, 64);
    }
    const int wid  = t >> 6;
    const int lane = t & 63;
    if (lane == 0) {
#pragma unroll
        for (int o = 0; o < NO; ++o) red[wid][o] = acc[o];
    }
    __syncthreads();

    if (t < NO) {
        const float v = red[0][t] + red[1][t] + red[2][t] + red[3][t];
        if (t < NT) {
            out[(size_t)br * NT + t] = v + bt[t];
        } else if (t < NT + NC) {
            const int o = t - NT;
            out[(size_t)BB * RR * NT + (size_t)br * NC + o] = v + bc[o];
        } else {
            const int o = t - NT - NC;
            out[(size_t)BB * RR * (NT + NC) + (size_t)br * NP + o] = v + bp[o];
        }
    }
}

extern "C" void kernel_launch(void* const* d_in, const int* in_sizes, int n_in,
                              void* d_out, int out_size, void* d_ws, size_t ws_size,
                              hipStream_t stream) {
    const float* hidden = (const float*)d_in[0];
    const int*   pairs  = (const int*)d_in[1];
    const int*   masks  = (const int*)d_in[2];
    const float* span   = (const float*)d_in[4];
    const float* segs   = (const float*)d_in[5];
    const float* Wt     = (const float*)d_in[6];
    const float* bt     = (const float*)d_in[7];
    const float* Wc     = (const float*)d_in[8];
    const float* bc     = (const float*)d_in[9];
    const float* Wp     = (const float*)d_in[10];
    const float* bp     = (const float*)d_in[11];
    float* out = (float*)d_out;
    float* ws  = (float*)d_ws;

    if (ws_size >= PART_ELEMS * sizeof(float)) {
        hipLaunchKernelGGL(p1_ctx, dim3(NB1), dim3(256), 0, stream,
                           hidden, masks, ws);
        hipLaunchKernelGGL(p2_head, dim3(BB * RR), dim3(256), 0, stream,
                           ws, pairs, span, segs, Wt, bt, Wc, bc, Wp, bp, out);
    } else {
        hipLaunchKernelGGL(rel_cls_fused, dim3(BB * RR), dim3(256), 0, stream,
                           hidden, pairs, masks, span, segs,
                           Wt, bt, Wc, bc, Wp, bp, out);
    }
}